// Round 6
// baseline (196.741 us; speedup 1.0000x reference)
//
#include <hip/hip_runtime.h>
#include <math.h>

#define BATCH 8
#define CH    64
#define HH    128
#define WW    128
#define HWSZ  (HH * WW)       // 16384
#define COUT  64
#define KTAPS 9
#define KDIM  576             // CH * KTAPS
#define LSTR  72              // ushorts per LDS px-row (transpose kernel)

typedef __attribute__((ext_vector_type(8))) short short8;
typedef __attribute__((ext_vector_type(4))) float f32x4;

__device__ __forceinline__ unsigned short f2bf(float f) {
    unsigned int u = __float_as_uint(f);
    u += 0x7fffu + ((u >> 16) & 1u);
    return (unsigned short)(u >> 16);
}
__device__ __forceinline__ float bflo(unsigned int u) { return __uint_as_float(u << 16); }
__device__ __forceinline__ float bfhi(unsigned int u) { return __uint_as_float(u & 0xffff0000u); }

// bilinear-combine one dword (2 bf16 channels) from 4 corners; pack via v_perm
__device__ __forceinline__ unsigned int bilin2(unsigned int a, unsigned int b,
                                               unsigned int c, unsigned int d,
                                               float w00, float w01, float w10, float w11) {
    float lo = w00 * bflo(a);
    lo = fmaf(w01, bflo(b), lo);
    lo = fmaf(w10, bflo(c), lo);
    lo = fmaf(w11, bflo(d), lo);
    float hi = w00 * bfhi(a);
    hi = fmaf(w01, bfhi(b), hi);
    hi = fmaf(w10, bfhi(c), hi);
    hi = fmaf(w11, bfhi(d), hi);
    return __builtin_amdgcn_perm(__float_as_uint(hi) + 0x8000u,
                                 __float_as_uint(lo) + 0x8000u, 0x07060302u);
}

// ---------------------------------------------------------------------------
// Kernel 0: NCHW fp32 -> NHWC bf16 transpose; blocks < 216 also repack conv
// weights into A-fragment-contiguous layouts:
//  wpk [kstep<18][mt<4][lane<64][8]  (main):  lane(n16,quad) holds
//      w_dcn[co=mt*16+n16][c = (kstep&1)*32 + quad*8 + j], tap = kstep>>1
//  wopk[kstep<18][mt<2][lane<64][8]  (offset, rows co>=27 zeroed)
// A-frag load = 64 lanes x 16 B contiguous = 1 KB coalesced.
// ---------------------------------------------------------------------------
__global__ __launch_bounds__(256) void transpose_x_kernel(
    const float* __restrict__ x, unsigned short* __restrict__ xt,
    const float* __restrict__ w_dcn, const float* __restrict__ w_off,
    unsigned short* __restrict__ wpk, unsigned short* __restrict__ wopk) {
    __shared__ unsigned short t[64 * LSTR];
    int tid = threadIdx.x, bid = blockIdx.x;

    if (bid < 216) {  // weight prep: 216*256 = 55296 = 36864 + 18432
        int j = bid * 256 + tid;
        if (j < 36864) {
            int jj = j & 7, ln = (j >> 3) & 63, mt = (j >> 9) & 3, ks = j >> 11;
            int tap = ks >> 1, h = ks & 1;
            int co = mt * 16 + (ln & 15);
            int c  = h * 32 + (ln >> 4) * 8 + jj;
            wpk[j] = f2bf(w_dcn[(co * CH + c) * KTAPS + tap]);
        } else {
            int jo = j - 36864;
            int jj = jo & 7, ln = (jo >> 3) & 63, mt = (jo >> 9) & 1, ks = jo >> 10;
            int tap = ks >> 1, h = ks & 1;
            int co = mt * 16 + (ln & 15);
            int c  = h * 32 + (ln >> 4) * 8 + jj;
            wopk[jo] = (co < 27) ? f2bf(w_off[(co * CH + c) * KTAPS + tap]) : 0;
        }
    }

    int b = bid >> 8;
    int pxbase = (bid & 255) * 64;
    int lane = tid & 63, wv = tid >> 6;
    const float* xb = x + (size_t)b * CH * HWSZ + pxbase;
#pragma unroll
    for (int i = 0; i < 16; ++i) {
        int c = wv * 16 + i;
        t[lane * LSTR + c] = f2bf(xb[(size_t)c * HWSZ + lane]);
    }
    __syncthreads();
    int px = tid >> 2, cp = (tid & 3) * 16;
    uint4 q0 = *(const uint4*)&t[px * LSTR + cp];
    uint4 q1 = *(const uint4*)&t[px * LSTR + cp + 8];
    unsigned short* o = xt + (size_t)(b * HWSZ + pxbase + px) * 64 + cp;
    *(uint4*)o = q0;
    *(uint4*)(o + 8) = q1;
}

// ---------------------------------------------------------------------------
// Kernel 1: FUSED, ZERO-BARRIER. Block = 64 px; wave w privately owns px
// quarter [w*16, w*16+16) for ALL co and ALL K. No cross-wave LDS sharing;
// no __syncthreads anywhere. Per wave:
//  Phase A: offset GEMM 32co x 16px (direct NHWC B-frags) -> omw (wave-LDS)
//  Phase B: bilinear params per (tap, own px) -> wgt/idx (wave-LDS)
//  Phase C: per tap: gather 4 corners per B-frag IN MFMA LAYOUT, combine,
//           MFMA vs packed A-frags; acc = 64co x 16px.
// LDS: omw 4x(32x17 f32)=8704 | wgt 4x(9x16 float4)=9216 | idx 4608 = 22528 B
// ---------------------------------------------------------------------------
__global__ __launch_bounds__(256) void dcn_fused_mfma(
    const unsigned short* __restrict__ xt, const unsigned short* __restrict__ wpk,
    const unsigned short* __restrict__ wopk, const float* __restrict__ b_off,
    const float* __restrict__ b_dcn, float* __restrict__ out) {
    __shared__ __align__(16) unsigned char smem[22528];
    float* omw = (float*)smem;                       // [w][32][17]
    float4* wgt = (float4*)(smem + 8704);            // [w][9][16]
    ushort4* idxA = (ushort4*)(smem + 17920);        // [w][9][16]

    int tid = threadIdx.x, bid = blockIdx.x;
    int b = bid & 7;                 // batch -> XCD pinning
    int pxbase = (bid >> 3) * 64;
    int lane = tid & 63, wv = tid >> 6;
    int quad = lane >> 4, n16 = lane & 15;

    const unsigned short* xb = xt + (size_t)b * HWSZ * 64;

    int pix = pxbase + wv * 16 + n16;     // this lane's pixel (all phases)
    int ho = pix >> 7, wo = pix & (WW - 1);

    float* omwW = omw + wv * (32 * 17);
    float4* wgtW = wgt + wv * (9 * 16);
    ushort4* idxW = idxA + wv * (9 * 16);

    // ---------------- Phase A: offset GEMM 32co x 16px ----------------
    {
        f32x4 oacc[2] = {{0, 0, 0, 0}, {0, 0, 0, 0}};
        for (int k = 0; k < KTAPS; ++k) {
            int ky = k / 3, kx = k - ky * 3;
            int yy = ho + ky - 1, xx = wo + kx - 1;
            bool v = (yy >= 0) & (yy < HH) & (xx >= 0) & (xx < WW);
            int sidx = v ? (yy * WW + xx) : 0;
#pragma unroll
            for (int h = 0; h < 2; ++h) {
                short8 bfrag = *(const short8*)(xb + (size_t)sidx * 64 + h * 32 + quad * 8);
                if (!v) bfrag = (short8)0;
#pragma unroll
                for (int mt = 0; mt < 2; ++mt) {
                    short8 afrag = *(const short8*)(wopk + (((k * 2 + h) * 2 + mt) * 64 + lane) * 8);
                    oacc[mt] = __builtin_amdgcn_mfma_f32_16x16x32_bf16(afrag, bfrag,
                                                                       oacc[mt], 0, 0, 0);
                }
            }
        }
        // C layout: row co = mt*16 + quad*4 + r, col px = n16
#pragma unroll
        for (int mt = 0; mt < 2; ++mt) {
#pragma unroll
            for (int r = 0; r < 4; ++r) {
                int row = mt * 16 + quad * 4 + r;
                if (row < 27) omwW[row * 17 + n16] = oacc[mt][r] + b_off[row];
            }
        }
    }
    // (no barrier: omw is wave-private; compiler orders via lgkmcnt)

    // ---------------- Phase B: params; quad q handles taps q, q+4, q+8 ----
    for (int t = quad; t < KTAPS; t += 4) {
        float fy = omwW[t * 17 + n16]        + (float)(ho - 1 + t / 3);
        float fx = omwW[(9 + t) * 17 + n16]  + (float)(wo - 1 + t % 3);
        float m  = 1.f / (1.f + __expf(-omwW[(18 + t) * 17 + n16]));
        float y0f = floorf(fy), x0f = floorf(fx);
        float dy = fy - y0f, dx = fx - x0f;
        int y0 = (int)y0f, x0i = (int)x0f;
        int y1 = y0 + 1, x1 = x0i + 1;
        bool vy0 = (y0 >= 0) & (y0 < HH);
        bool vy1 = (y1 >= 0) & (y1 < HH);
        bool vx0 = (x0i >= 0) & (x0i < WW);
        bool vx1 = (x1 >= 0) & (x1 < WW);
        float w00 = (1.f - dy) * (1.f - dx) * m; if (!(vy0 && vx0)) w00 = 0.f;
        float w01 = (1.f - dy) * dx * m;         if (!(vy0 && vx1)) w01 = 0.f;
        float w10 = dy * (1.f - dx) * m;         if (!(vy1 && vx0)) w10 = 0.f;
        float w11 = dy * dx * m;                 if (!(vy1 && vx1)) w11 = 0.f;
        int yc0 = min(max(y0, 0), HH - 1), yc1 = min(max(y1, 0), HH - 1);
        int xc0 = min(max(x0i, 0), WW - 1), xc1 = min(max(x1, 0), WW - 1);
        wgtW[t * 16 + n16] = make_float4(w00, w01, w10, w11);
        idxW[t * 16 + n16] = make_ushort4((unsigned short)(yc0 * WW + xc0),
                                          (unsigned short)(yc0 * WW + xc1),
                                          (unsigned short)(yc1 * WW + xc0),
                                          (unsigned short)(yc1 * WW + xc1));
    }
    // (no barrier: wgt/idx wave-private)

    // ---------------- Phase C: main GEMM 64co x 16px ----------------
    f32x4 acc[4] = {{0, 0, 0, 0}, {0, 0, 0, 0}, {0, 0, 0, 0}, {0, 0, 0, 0}};

    for (int k = 0; k < KTAPS; ++k) {
        float4 w4 = wgtW[k * 16 + n16];      // broadcast across quads
        ushort4 i4 = idxW[k * 16 + n16];
#pragma unroll
        for (int h = 0; h < 2; ++h) {
            int coff = h * 32 + quad * 8;
            uint4 qa = *(const uint4*)(xb + (size_t)i4.x * 64 + coff);
            uint4 qb = *(const uint4*)(xb + (size_t)i4.y * 64 + coff);
            uint4 qc = *(const uint4*)(xb + (size_t)i4.z * 64 + coff);
            uint4 qd = *(const uint4*)(xb + (size_t)i4.w * 64 + coff);
            unsigned int bf[4];
            bf[0] = bilin2(qa.x, qb.x, qc.x, qd.x, w4.x, w4.y, w4.z, w4.w);
            bf[1] = bilin2(qa.y, qb.y, qc.y, qd.y, w4.x, w4.y, w4.z, w4.w);
            bf[2] = bilin2(qa.z, qb.z, qc.z, qd.z, w4.x, w4.y, w4.z, w4.w);
            bf[3] = bilin2(qa.w, qb.w, qc.w, qd.w, w4.x, w4.y, w4.z, w4.w);
            short8 bfrag = *(const short8*)bf;
#pragma unroll
            for (int mt = 0; mt < 4; ++mt) {
                short8 afrag = *(const short8*)(wpk + (((k * 2 + h) * 4 + mt) * 64 + lane) * 8);
                acc[mt] = __builtin_amdgcn_mfma_f32_16x16x32_bf16(afrag, bfrag,
                                                                  acc[mt], 0, 0, 0);
            }
        }
    }

    // Epilogue: direct stores; wave owns its px columns. co = mt*16+quad*4+r
    float* ob = out + (size_t)b * COUT * HWSZ + pix;
#pragma unroll
    for (int mt = 0; mt < 4; ++mt) {
#pragma unroll
        for (int r = 0; r < 4; ++r) {
            int co = mt * 16 + quad * 4 + r;
            ob[(size_t)co * HWSZ] = acc[mt][r] + b_dcn[co];
        }
    }
}

// ---------------------------------------------------------------------------
extern "C" void kernel_launch(void* const* d_in, const int* in_sizes, int n_in,
                              void* d_out, int out_size, void* d_ws, size_t ws_size,
                              hipStream_t stream) {
    const float* x     = (const float*)d_in[0];
    const float* w_off = (const float*)d_in[1];
    const float* b_off = (const float*)d_in[2];
    const float* w_dcn = (const float*)d_in[3];
    const float* b_dcn = (const float*)d_in[4];
    float* out = (float*)d_out;

    // ws layout: xt (bf16 NHWC, 16 MB) | wpk | wopk
    unsigned short* xt   = (unsigned short*)d_ws;
    unsigned short* wpk  = xt + (size_t)BATCH * HWSZ * 64;   // 36864
    unsigned short* wopk = wpk + 36864;                      // 18432

    hipLaunchKernelGGL(transpose_x_kernel, dim3(2048), dim3(256), 0, stream,
                       x, xt, w_dcn, w_off, wpk, wopk);
    hipLaunchKernelGGL(dcn_fused_mfma, dim3(BATCH * HWSZ / 64), dim3(256),
                       0, stream, xt, wpk, wopk, b_off, b_dcn, out);
}

// Round 7
// 138.805 us; speedup vs baseline: 1.4174x; 1.4174x over previous
//
#include <hip/hip_runtime.h>
#include <math.h>

#define BATCH 8
#define CH    64
#define HH    128
#define WW    128
#define HWSZ  (HH * WW)       // 16384
#define COUT  64
#define KTAPS 9
#define KDIM  576             // CH * KTAPS
#define LSTR  72              // ushorts per LDS px-row (144 B)

typedef __attribute__((ext_vector_type(8))) short short8;
typedef __attribute__((ext_vector_type(4))) float f32x4;
typedef __attribute__((ext_vector_type(2))) float f32x2;

__device__ __forceinline__ unsigned short f2bf(float f) {
    unsigned int u = __float_as_uint(f);
    u += 0x7fffu + ((u >> 16) & 1u);
    return (unsigned short)(u >> 16);
}
// unpack dword (2 bf16 ch) -> f32x2 {lo, hi}
__device__ __forceinline__ f32x2 up2(unsigned int u) {
    f32x2 r;
    r.x = __uint_as_float(u << 16);
    r.y = __uint_as_float(u & 0xffff0000u);
    return r;
}
// bilinear-combine one dword from 4 corners via packed-f32 math; v_perm pack
__device__ __forceinline__ unsigned int bilin2(unsigned int a, unsigned int b,
                                               unsigned int c, unsigned int d,
                                               float w00, float w01, float w10, float w11) {
    f32x2 acc = up2(a) * w00;
    acc = up2(b) * w01 + acc;
    acc = up2(c) * w10 + acc;
    acc = up2(d) * w11 + acc;
    return __builtin_amdgcn_perm(__float_as_uint(acc.y) + 0x8000u,
                                 __float_as_uint(acc.x) + 0x8000u, 0x07060302u);
}

// ---------------------------------------------------------------------------
// Kernel 0: NCHW fp32 -> NHWC bf16 transpose; blocks < 216 also repack conv
// weights into WAVE-CONTIGUOUS A-fragment layouts (1 KB = 8 full lines/instr):
//  wpk [mt<4][ks<18][lane<64][8]: lane(n16,quad) holds
//      w_dcn[co=mt*16+n16][c=(ks&1)*32+quad*8+j], tap=ks>>1
//  wopk[cot<2][ks<18][lane<64][8]: same for w_off (co>=27 zeroed)
// ---------------------------------------------------------------------------
__global__ __launch_bounds__(256) void transpose_x_kernel(
    const float* __restrict__ x, unsigned short* __restrict__ xt,
    const float* __restrict__ w_dcn, const float* __restrict__ w_off,
    unsigned short* __restrict__ wpk, unsigned short* __restrict__ wopk) {
    __shared__ unsigned short t[64 * LSTR];
    int tid = threadIdx.x, bid = blockIdx.x;

    if (bid < 216) {  // weight prep: 216*256 = 55296 = 36864 + 18432
        int j = bid * 256 + tid;
        if (j < 36864) {
            int jj = j & 7, ln = (j >> 3) & 63, q = j >> 9;   // q: 0..71
            int ks = q % 18, mt = q / 18;
            int tap = ks >> 1, h = ks & 1;
            int co = mt * 16 + (ln & 15);
            int c  = h * 32 + (ln >> 4) * 8 + jj;
            wpk[j] = f2bf(w_dcn[(co * CH + c) * KTAPS + tap]);
        } else {
            int jo = j - 36864;
            int jj = jo & 7, ln = (jo >> 3) & 63, q = jo >> 9; // q: 0..35
            int ks = q % 18, cot = q / 18;
            int tap = ks >> 1, h = ks & 1;
            int co = cot * 16 + (ln & 15);
            int c  = h * 32 + (ln >> 4) * 8 + jj;
            wopk[jo] = (co < 27) ? f2bf(w_off[(co * CH + c) * KTAPS + tap]) : 0;
        }
    }

    int b = bid >> 8;
    int pxbase = (bid & 255) * 64;
    int lane = tid & 63, wv = tid >> 6;
    const float* xb = x + (size_t)b * CH * HWSZ + pxbase;
#pragma unroll
    for (int i = 0; i < 16; ++i) {
        int c = wv * 16 + i;
        t[lane * LSTR + c] = f2bf(xb[(size_t)c * HWSZ + lane]);
    }
    __syncthreads();
    int px = tid >> 2, cp = (tid & 3) * 16;
    uint4 q0 = *(const uint4*)&t[px * LSTR + cp];
    uint4 q1 = *(const uint4*)&t[px * LSTR + cp + 8];
    unsigned short* o = xt + (size_t)(b * HWSZ + pxbase + px) * 64 + cp;
    *(uint4*)o = q0;
    *(uint4*)(o + 8) = q1;
}

// ---------------------------------------------------------------------------
// Kernel 1: FUSED DCN, co-split waves, 3-tap LDS rounds.
//  Phase 1 (x3 rounds): stage raw x cols for 3 taps (full-line gathers,
//      (px8,ch8) lane map) -> barrier -> offset MFMA 32co x 64px -> barrier.
//  omr[27][64] <- oacc + bias.
//  Phase 2: bilinear params per (tap,px) -> wgt float4 / idx ushort4.
//  Phase 3 (x3 rounds): bilinear col build for 3 taps -> barrier ->
//      main MFMA 64co x 64px (A from wave-contiguous wpk) -> barrier.
// LDS: colL 27648 | omr 6912 | wgt 9216 | idx 4608 = 48384 B (3 blk/CU)
// ---------------------------------------------------------------------------
__global__ __launch_bounds__(256) void dcn_fused_mfma(
    const unsigned short* __restrict__ xt, const unsigned short* __restrict__ wpk,
    const unsigned short* __restrict__ wopk, const float* __restrict__ b_off,
    const float* __restrict__ b_dcn, float* __restrict__ out) {
    __shared__ __align__(16) unsigned char smem[48384];
    unsigned short* colL = (unsigned short*)smem;          // 3 x 64 x LSTR
    float* omr = (float*)(smem + 27648);                   // [27][64]
    float4* wgt = (float4*)(smem + 34560);                 // [9][64]
    ushort4* idxA = (ushort4*)(smem + 43776);              // [9][64]

    int tid = threadIdx.x, bid = blockIdx.x;
    int b = bid & 7;                 // batch -> XCD pinning
    int pxbase = (bid >> 3) * 64;
    int lane = tid & 63, wv = tid >> 6;
    int quad = lane >> 4, n16 = lane & 15;
    int h8 = lane & 7, p8 = lane >> 3;

    const unsigned short* xb = xt + (size_t)b * HWSZ * 64;

    // ---------------- Phase 1: offset conv GEMM (3-tap rounds) ------------
    {
        int coh = (wv & 1);              // co-tile 0/1
        int pxh = (wv >> 1) * 32;        // px half
        f32x4 oacc[2] = {{0, 0, 0, 0}, {0, 0, 0, 0}};
        for (int r3 = 0; r3 < 3; ++r3) {
#pragma unroll
            for (int t3 = 0; t3 < 3; ++t3) {
                int k = r3 * 3 + t3;
                int ky = k / 3, kx = k - ky * 3;
#pragma unroll
                for (int s = 0; s < 2; ++s) {
                    int pl = wv * 16 + s * 8 + p8;
                    int pix = pxbase + pl;
                    int yy = (pix >> 7) + ky - 1, xx = (pix & (WW - 1)) + kx - 1;
                    bool v = (yy >= 0) & (yy < HH) & (xx >= 0) & (xx < WW);
                    int sidx = v ? (yy * WW + xx) : 0;
                    uint4 q = *(const uint4*)(xb + (size_t)sidx * 64 + h8 * 8);
                    if (!v) { q.x = q.y = q.z = q.w = 0; }
                    *(uint4*)&colL[(t3 * 64 + pl) * LSTR + h8 * 8] = q;
                }
            }
            __syncthreads();
#pragma unroll
            for (int t3 = 0; t3 < 3; ++t3) {
                int k = r3 * 3 + t3;
#pragma unroll
                for (int h = 0; h < 2; ++h) {
                    short8 afrag = *(const short8*)(wopk + (size_t)((coh * 18 + k * 2 + h) * 64 + lane) * 8);
#pragma unroll
                    for (int pt = 0; pt < 2; ++pt) {
                        short8 bfrag = *(const short8*)(&colL[(t3 * 64 + pxh + pt * 16 + n16) * LSTR + h * 32 + quad * 8]);
                        oacc[pt] = __builtin_amdgcn_mfma_f32_16x16x32_bf16(afrag, bfrag,
                                                                           oacc[pt], 0, 0, 0);
                    }
                }
            }
            __syncthreads();
        }
        // C layout: row co = coh*16 + quad*4 + r, col px = pxh + pt*16 + n16
#pragma unroll
        for (int pt = 0; pt < 2; ++pt) {
#pragma unroll
            for (int r = 0; r < 4; ++r) {
                int co = coh * 16 + quad * 4 + r;
                if (co < 27) omr[co * 64 + pxh + pt * 16 + n16] = oacc[pt][r] + b_off[co];
            }
        }
    }
    __syncthreads();

    // ---------------- Phase 2: bilinear params -> wgt/idx ----------------
    for (int j = tid; j < KTAPS * 64; j += 256) {
        int tap = j >> 6, pl = j & 63;
        int pix = pxbase + pl, ho = pix >> 7, wo = pix & (WW - 1);
        float fy = omr[tap * 64 + pl] + (float)(ho - 1 + tap / 3);
        float fx = omr[(9 + tap) * 64 + pl] + (float)(wo - 1 + tap % 3);
        float m = 1.f / (1.f + __expf(-omr[(18 + tap) * 64 + pl]));
        float y0f = floorf(fy), x0f = floorf(fx);
        float dy = fy - y0f, dx = fx - x0f;
        int y0 = (int)y0f, x0i = (int)x0f;
        int y1 = y0 + 1, x1 = x0i + 1;
        bool vy0 = (y0 >= 0) & (y0 < HH);
        bool vy1 = (y1 >= 0) & (y1 < HH);
        bool vx0 = (x0i >= 0) & (x0i < WW);
        bool vx1 = (x1 >= 0) & (x1 < WW);
        float w00 = (1.f - dy) * (1.f - dx) * m; if (!(vy0 && vx0)) w00 = 0.f;
        float w01 = (1.f - dy) * dx * m;         if (!(vy0 && vx1)) w01 = 0.f;
        float w10 = dy * (1.f - dx) * m;         if (!(vy1 && vx0)) w10 = 0.f;
        float w11 = dy * dx * m;                 if (!(vy1 && vx1)) w11 = 0.f;
        int yc0 = min(max(y0, 0), HH - 1), yc1 = min(max(y1, 0), HH - 1);
        int xc0 = min(max(x0i, 0), WW - 1), xc1 = min(max(x1, 0), WW - 1);
        wgt[j] = make_float4(w00, w01, w10, w11);
        idxA[j] = make_ushort4((unsigned short)(yc0 * WW + xc0),
                               (unsigned short)(yc0 * WW + xc1),
                               (unsigned short)(yc1 * WW + xc0),
                               (unsigned short)(yc1 * WW + xc1));
    }
    __syncthreads();

    // ---------------- Phase 3: main GEMM (3-tap rounds) ----------------
    f32x4 acc[4] = {{0, 0, 0, 0}, {0, 0, 0, 0}, {0, 0, 0, 0}, {0, 0, 0, 0}};

    for (int r3 = 0; r3 < 3; ++r3) {
#pragma unroll
        for (int t3 = 0; t3 < 3; ++t3) {
            int k = r3 * 3 + t3;
#pragma unroll
            for (int s = 0; s < 2; ++s) {
                int pl = wv * 16 + s * 8 + p8;
                float4 w4 = wgt[k * 64 + pl];
                ushort4 i4 = idxA[k * 64 + pl];
                uint4 qa = *(const uint4*)(xb + (size_t)i4.x * 64 + h8 * 8);
                uint4 qb = *(const uint4*)(xb + (size_t)i4.y * 64 + h8 * 8);
                uint4 qc = *(const uint4*)(xb + (size_t)i4.z * 64 + h8 * 8);
                uint4 qd = *(const uint4*)(xb + (size_t)i4.w * 64 + h8 * 8);
                uint4 r;
                r.x = bilin2(qa.x, qb.x, qc.x, qd.x, w4.x, w4.y, w4.z, w4.w);
                r.y = bilin2(qa.y, qb.y, qc.y, qd.y, w4.x, w4.y, w4.z, w4.w);
                r.z = bilin2(qa.z, qb.z, qc.z, qd.z, w4.x, w4.y, w4.z, w4.w);
                r.w = bilin2(qa.w, qb.w, qc.w, qd.w, w4.x, w4.y, w4.z, w4.w);
                *(uint4*)&colL[(t3 * 64 + pl) * LSTR + h8 * 8] = r;
            }
        }
        __syncthreads();
#pragma unroll
        for (int t3 = 0; t3 < 3; ++t3) {
            int k = r3 * 3 + t3;
#pragma unroll
            for (int h = 0; h < 2; ++h) {
                short8 afrag = *(const short8*)(wpk + (size_t)((wv * 18 + k * 2 + h) * 64 + lane) * 8);
#pragma unroll
                for (int pt = 0; pt < 4; ++pt) {
                    short8 bfrag = *(const short8*)(&colL[(t3 * 64 + pt * 16 + n16) * LSTR + h * 32 + quad * 8]);
                    acc[pt] = __builtin_amdgcn_mfma_f32_16x16x32_bf16(afrag, bfrag,
                                                                      acc[pt], 0, 0, 0);
                }
            }
        }
        __syncthreads();
    }

    // Epilogue: D[m = quad*4+r][n = n16], co = wv*16 + m
    float* ob = out + (size_t)b * COUT * HWSZ;
#pragma unroll
    for (int pt = 0; pt < 4; ++pt) {
        int px = pxbase + pt * 16 + n16;
#pragma unroll
        for (int r = 0; r < 4; ++r) {
            int co = wv * 16 + quad * 4 + r;
            ob[(size_t)co * HWSZ + px] = acc[pt][r] + b_dcn[co];
        }
    }
}

// ---------------------------------------------------------------------------
extern "C" void kernel_launch(void* const* d_in, const int* in_sizes, int n_in,
                              void* d_out, int out_size, void* d_ws, size_t ws_size,
                              hipStream_t stream) {
    const float* x     = (const float*)d_in[0];
    const float* w_off = (const float*)d_in[1];
    const float* b_off = (const float*)d_in[2];
    const float* w_dcn = (const float*)d_in[3];
    const float* b_dcn = (const float*)d_in[4];
    float* out = (float*)d_out;

    // ws layout: xt (bf16 NHWC, 16 MB) | wpk | wopk
    unsigned short* xt   = (unsigned short*)d_ws;
    unsigned short* wpk  = xt + (size_t)BATCH * HWSZ * 64;   // 36864
    unsigned short* wopk = wpk + 36864;                      // 18432

    hipLaunchKernelGGL(transpose_x_kernel, dim3(2048), dim3(256), 0, stream,
                       x, xt, w_dcn, w_off, wpk, wopk);
    hipLaunchKernelGGL(dcn_fused_mfma, dim3(BATCH * HWSZ / 64), dim3(256),
                       0, stream, xt, wpk, wopk, b_off, b_dcn, out);
}